// Round 8
// baseline (573.239 us; speedup 1.0000x reference)
//
#include <hip/hip_runtime.h>
#include <stdint.h>

typedef __attribute__((ext_vector_type(8))) __bf16 bf16x8;
typedef __attribute__((ext_vector_type(4))) __bf16 bf16x4;
typedef __attribute__((ext_vector_type(4))) float f32x4;
typedef unsigned short u16;

#define D_MODEL 1024
#define D_FF 4096
#define SEQ 2048
#define NHEAD 16
#define DH 64
#define MROWS 8192

__device__ __forceinline__ u16 f2bf(float f) {
  union { float f; unsigned u; } v; v.f = f;
  unsigned r = v.u + 0x7fffu + ((v.u >> 16) & 1u);
  return (u16)(r >> 16);
}

// async global->LDS, 16B per lane; lds dest wave-uniform base (+lane*16 implicit)
__device__ __forceinline__ void gload16(const u16* g, u16* l) {
  __builtin_amdgcn_global_load_lds((const __attribute__((address_space(1))) void*)(g),
                                   (__attribute__((address_space(3))) void*)(l),
                                   16, 0, 0);
}

// raw barrier (no vmcnt/lgkmcnt drain) + compiler memory fence both sides
__device__ __forceinline__ void block_bar() {
  asm volatile("" ::: "memory");
  __builtin_amdgcn_s_barrier();
  asm volatile("" ::: "memory");
}

template <int N>
__device__ __forceinline__ void wait_vm() {
  if constexpr (N == 6)      asm volatile("s_waitcnt vmcnt(6)" ::: "memory");
  else if constexpr (N == 4) asm volatile("s_waitcnt vmcnt(4)" ::: "memory");
  else                       asm volatile("s_waitcnt vmcnt(0)" ::: "memory");
}

// ---------------- weight f32 [K][N] -> bf16 transposed [N][K] (optional scale) ----
__global__ __launch_bounds__(256)
void wconv_kernel(const float* __restrict__ W, u16* __restrict__ Wt, int K, int N,
                  float scale) {
  __shared__ u16 t[32][33];
  const int tid = threadIdx.x, tx = tid & 31, ty = tid >> 5;
  const int n0 = blockIdx.x * 32, k0 = blockIdx.y * 32;
#pragma unroll
  for (int i = 0; i < 4; ++i) {
    int k = ty + i * 8;
    t[k][tx] = f2bf(W[(size_t)(k0 + k) * N + n0 + tx] * scale);
  }
  __syncthreads();
#pragma unroll
  for (int i = 0; i < 4; ++i) {
    int n = ty + i * 8;
    Wt[(size_t)(n0 + n) * K + k0 + tx] = t[tx][n];
  }
}

// ---------------- layernorm: f32 [row][1024] -> bf16 ----------------
__global__ __launch_bounds__(256)
void ln_kernel(const float* __restrict__ x, u16* __restrict__ out,
               const float* __restrict__ g, const float* __restrict__ beta) {
  const int row = blockIdx.x, tid = threadIdx.x;
  const float4 v = reinterpret_cast<const float4*>(x + (size_t)row * D_MODEL)[tid];
  float s = v.x + v.y + v.z + v.w;
#pragma unroll
  for (int off = 32; off; off >>= 1) s += __shfl_down(s, off);
  __shared__ float red[8];
  if ((tid & 63) == 0) red[tid >> 6] = s;
  __syncthreads();
  const float mu = (red[0] + red[1] + red[2] + red[3]) * (1.0f / D_MODEL);
  const float dx = v.x - mu, dy = v.y - mu, dz = v.z - mu, dw = v.w - mu;
  float sq = dx * dx + dy * dy + dz * dz + dw * dw;
#pragma unroll
  for (int off = 32; off; off >>= 1) sq += __shfl_down(sq, off);
  if ((tid & 63) == 0) red[4 + (tid >> 6)] = sq;
  __syncthreads();
  const float var = (red[4] + red[5] + red[6] + red[7]) * (1.0f / D_MODEL);
  const float rs = rsqrtf(var + 1e-5f);
  const float4 gv = reinterpret_cast<const float4*>(g)[tid];
  const float4 bv = reinterpret_cast<const float4*>(beta)[tid];
  ushort4 ov;
  ov.x = f2bf(dx * rs * gv.x + bv.x);
  ov.y = f2bf(dy * rs * gv.y + bv.y);
  ov.z = f2bf(dz * rs * gv.z + bv.z);
  ov.w = f2bf(dw * rs * gv.w + bv.w);
  reinterpret_cast<ushort4*>(out + (size_t)row * D_MODEL)[tid] = ov;
}

// ======== 8-phase TN GEMM (m201 template): BMx256 tile, BK=64, 8 waves (2x4) ====
// (round-6 measured-best config, reverted: BM=128 -> 8 phases, MI=MREP/4)
template <int BM, int EPI>
__global__ __launch_bounds__(512, 2)
void gemm8p_kernel(const u16* __restrict__ A, const u16* __restrict__ Bt,
                   int N, int K,
                   const float* __restrict__ bias,
                   const float* __restrict__ res,
                   float* __restrict__ outf, u16* __restrict__ outb,
                   u16* __restrict__ outb2, u16* __restrict__ outb3) {
  constexpr int WM = BM / 2;
  constexpr int MREP = WM / 16;
  constexpr int MI = MREP / 4;
  constexpr int ACH = BM / 64;
  constexpr int VN = (BM == 256) ? 6 : 4;
  __shared__ __align__(16) u16 Al[2][BM * 64];
  __shared__ __align__(16) u16 Bl[2][256 * 64];
  const int tid = threadIdx.x, lane = tid & 63, wave = tid >> 6;
  const int wr = wave >> 2, wc = wave & 3;
  const int l16 = lane & 15, g8 = lane >> 4;
  const int srw = lane >> 3;
  const int scl = ((lane & 7) ^ (lane >> 3)) * 8;
  const int swz = (l16 & 7) << 3;
  const int mBase = blockIdx.y * BM, nBase = blockIdx.x * 256;
  const int nt = K >> 6;

  f32x4 acc[MREP][4];
#pragma unroll
  for (int mi = 0; mi < MREP; ++mi)
#pragma unroll
    for (int nj = 0; nj < 4; ++nj) acc[mi][nj] = f32x4{0.f, 0.f, 0.f, 0.f};

  auto stageChunk = [&](int tile, int c) {
    if (tile >= nt) return;
    const int buf = tile & 1;
    if (c < ACH) {
      const int r0 = c * 64 + wave * 8;
      gload16(A + (size_t)(mBase + r0 + srw) * K + tile * 64 + scl,
              &Al[buf][r0 * 64]);
    } else {
      const int r0 = (c - ACH) * 64 + wave * 8;
      gload16(Bt + (size_t)(nBase + r0 + srw) * K + tile * 64 + scl,
              &Bl[buf][r0 * 64]);
    }
  };

  constexpr int STO256[16] = {1,1, 2,2, 2,2, 2,2, 2,2, 3,3, 3,3, 3,3};
  constexpr int STC256[16] = {1,3, 4,5, 6,7, 0,2, 1,3, 4,5, 6,7, 0,2};
  constexpr int STO128[16] = {1,1, 2,2, 2,2, 0,0, 2,2, 3,3, 3,3, 0,0};
  constexpr int STC128[16] = {0,1, 2,3, 4,5, -1,-1, 0,1, 2,3, 4,5, -1,-1};

  constexpr int P0_256[8] = {4,5,6,7,0,2,1,3};
  constexpr int P1_256[6] = {4,5,6,7,0,2};
  constexpr int P0_128[6] = {2,3,4,5,0,1};
  constexpr int P1_128[4] = {2,3,4,5};
  if constexpr (BM == 256) {
#pragma unroll
    for (int i = 0; i < 8; ++i) stageChunk(0, P0_256[i]);
#pragma unroll
    for (int i = 0; i < 6; ++i) stageChunk(1, P1_256[i]);
  } else {
#pragma unroll
    for (int i = 0; i < 6; ++i) stageChunk(0, P0_128[i]);
#pragma unroll
    for (int i = 0; i < 4; ++i) stageChunk(1, P1_128[i]);
  }
  wait_vm<VN>();
  block_bar();

  for (int T = 0; T < nt; T += 2) {
    bf16x8 bfr[4][2];
#pragma unroll
    for (int p = 0; p < 8; ++p) {
      const int q = p & 3;
      const int buf = p >> 2;
      if (q == 0) {
#pragma unroll
        for (int nj = 0; nj < 4; ++nj)
#pragma unroll
          for (int ks = 0; ks < 2; ++ks) {
            const int rb = wc * 64 + nj * 16 + l16;
            bfr[nj][ks] = *reinterpret_cast<const bf16x8*>(
                &Bl[buf][rb * 64 + ((ks * 32 + g8 * 8) ^ swz)]);
          }
      }
      bf16x8 af[MI][2];
#pragma unroll
      for (int i = 0; i < MI; ++i)
#pragma unroll
        for (int ks = 0; ks < 2; ++ks) {
          const int ra = wr * WM + (q * MI + i) * 16 + l16;
          af[i][ks] = *reinterpret_cast<const bf16x8*>(
              &Al[buf][ra * 64 + ((ks * 32 + g8 * 8) ^ swz)]);
        }
      if constexpr (BM == 256) {
        stageChunk(T + STO256[2 * p], STC256[2 * p]);
        stageChunk(T + STO256[2 * p + 1], STC256[2 * p + 1]);
      } else {
        if (STC128[2 * p] >= 0) {
          stageChunk(T + STO128[2 * p], STC128[2 * p]);
          stageChunk(T + STO128[2 * p + 1], STC128[2 * p + 1]);
        }
      }
      block_bar();
      __builtin_amdgcn_s_setprio(1);
#pragma unroll
      for (int i = 0; i < MI; ++i)
#pragma unroll
        for (int nj = 0; nj < 4; ++nj)
#pragma unroll
          for (int ks = 0; ks < 2; ++ks)
            acc[q * MI + i][nj] = __builtin_amdgcn_mfma_f32_16x16x32_bf16(
                af[i][ks], bfr[nj][ks], acc[q * MI + i][nj], 0, 0, 0);
      __builtin_amdgcn_s_setprio(0);
      if (p == 3) {
        if (T + 2 < nt) wait_vm<VN>(); else wait_vm<0>();
      } else if (p == 7) {
        wait_vm<VN>();
      }
      block_bar();
    }
  }

#pragma unroll
  for (int mi = 0; mi < MREP; ++mi)
#pragma unroll
    for (int nj = 0; nj < 4; ++nj) {
      const int colB = wc * 64 + nj * 16 + l16;
      const int row0 = mBase + wr * WM + mi * 16 + g8 * 4;
      if (EPI == 4) {
        const int seg = nBase >> 10;
        const int c = (nBase & 1023) + colB;
        if (seg == 2) {
          const int bi = row0 >> 11, s = row0 & 2047;
          ushort4 pk;
          pk.x = f2bf(acc[mi][nj][0]);
          pk.y = f2bf(acc[mi][nj][1]);
          pk.z = f2bf(acc[mi][nj][2]);
          pk.w = f2bf(acc[mi][nj][3]);
          *reinterpret_cast<ushort4*>(outb3 + ((size_t)(bi << 10) + c) * SEQ + s) = pk;
        } else {
          u16* o = (seg == 0) ? outb : outb2;
#pragma unroll
          for (int r = 0; r < 4; ++r)
            o[(size_t)(row0 + r) * D_MODEL + c] = f2bf(acc[mi][nj][r]);
        }
      } else {
        const int col = nBase + colB;
        const float bv = bias[col];
#pragma unroll
        for (int r = 0; r < 4; ++r) {
          const size_t idx = (size_t)(row0 + r) * N + col;
          const float vv = acc[mi][nj][r];
          if (EPI == 1) {
            outf[idx] = vv + bv + res[idx];
          } else {
            const float tv = vv + bv;
            outb[idx] = f2bf(tv > 0.f ? tv : 0.f);
          }
        }
      }
    }
}

// ---------------- flash attention: 4 waves x 64 q-rows, KV tile 64 ----------------
// Swapped QK^T; async dbuf KV; exp2 (scale folded in wq); defer-max (T13).
// Per-wave Q = 64 rows (m=0..3) -> per-tile fixed costs (K/V frag reads, stage,
// barriers) amortized over 2x the q-rows vs QBLK=32. vb is V^T per batch.
__global__ __launch_bounds__(256)
void attn_kernel(const u16* __restrict__ qb, const u16* __restrict__ kb,
                 const u16* __restrict__ vb, u16* __restrict__ ctx) {
  __shared__ __align__(16) u16 Kl[2][64 * 64];
  __shared__ __align__(16) u16 Vl[2][64 * 64];   // V^T tile: Vl[d][t]
  __shared__ __align__(16) u16 Pl[4][64 * 64];   // per-wave P: [q 64][kv 64]
  const int tid = threadIdx.x;
  const int lane = tid & 63, wave = tid >> 6, g8 = lane >> 4, l16 = lane & 15;
  const int b = blockIdx.y >> 4, h = blockIdx.y & 15;
  const int q0 = blockIdx.x * 256 + wave * 64;
  const size_t rowB = (size_t)b * SEQ;
  const int colH = h * DH;
  const size_t vtBase = (size_t)(b * 1024 + colH) * SEQ;
  const int srw = lane >> 3;
  const int scl = ((lane & 7) ^ (lane >> 3)) * 8;
  const int cswz = (l16 & 7) * 8;

  bf16x8 qf[4][2];
#pragma unroll
  for (int m = 0; m < 4; ++m)
#pragma unroll
    for (int ks = 0; ks < 2; ++ks)
      qf[m][ks] = *reinterpret_cast<const bf16x8*>(
          qb + (rowB + q0 + m * 16 + l16) * D_MODEL + colH + ks * 32 + g8 * 8);

  float mi[4] = {-1e30f, -1e30f, -1e30f, -1e30f}, li[4] = {0.f, 0.f, 0.f, 0.f};
  f32x4 o[4][4];
#pragma unroll
  for (int m = 0; m < 4; ++m)
#pragma unroll
    for (int nt = 0; nt < 4; ++nt) o[m][nt] = f32x4{0.f, 0.f, 0.f, 0.f};

  auto stageKV = [&](int t0, int buf) {
    if (t0 >= SEQ) return;
#pragma unroll
    for (int i = 0; i < 2; ++i) {
      const int r0 = wave * 16 + i * 8;
      gload16(kb + (rowB + t0 + r0 + srw) * D_MODEL + colH + scl, &Kl[buf][r0 * 64]);
      gload16(vb + vtBase + (size_t)(r0 + srw) * SEQ + t0 + scl, &Vl[buf][r0 * 64]);
    }
  };

  stageKV(0, 0);
  wait_vm<0>();
  block_bar();

  int buf = 0;
  for (int t0 = 0; t0 < SEQ; t0 += 64, buf ^= 1) {
    stageKV(t0 + 64, buf ^ 1);

    // S^T tiles: st[m][kt], rows kv = kt*16+g8*4+r, cols q = m*16+l16
    f32x4 st[4][4];
#pragma unroll
    for (int m = 0; m < 4; ++m)
#pragma unroll
      for (int kt = 0; kt < 4; ++kt) st[m][kt] = f32x4{0.f, 0.f, 0.f, 0.f};
#pragma unroll
    for (int kt = 0; kt < 4; ++kt) {
      const bf16x8 kf0 = *reinterpret_cast<const bf16x8*>(
          &Kl[buf][(kt * 16 + l16) * 64 + ((g8 * 8) ^ cswz)]);
      const bf16x8 kf1 = *reinterpret_cast<const bf16x8*>(
          &Kl[buf][(kt * 16 + l16) * 64 + ((32 + g8 * 8) ^ cswz)]);
#pragma unroll
      for (int m = 0; m < 4; ++m) {
        st[m][kt] = __builtin_amdgcn_mfma_f32_16x16x32_bf16(kf0, qf[m][0], st[m][kt], 0, 0, 0);
        st[m][kt] = __builtin_amdgcn_mfma_f32_16x16x32_bf16(kf1, qf[m][1], st[m][kt], 0, 0, 0);
      }
    }

    float alpha[4];
    bool dor[4];
#pragma unroll
    for (int m = 0; m < 4; ++m) {
      float pmax = st[m][0][0];
#pragma unroll
      for (int kt = 0; kt < 4; ++kt)
#pragma unroll
        for (int r = 0; r < 4; ++r) pmax = fmaxf(pmax, st[m][kt][r]);
      pmax = fmaxf(pmax, __shfl_xor(pmax, 16));
      pmax = fmaxf(pmax, __shfl_xor(pmax, 32));
      dor[m] = !__all(pmax - mi[m] <= 8.0f);
      alpha[m] = 1.0f;
      if (dor[m]) {
        const float mnew = fmaxf(mi[m], pmax);
        alpha[m] = __builtin_amdgcn_exp2f(mi[m] - mnew);
        mi[m] = mnew;
      }
      float sum = 0.f;
#pragma unroll
      for (int kt = 0; kt < 4; ++kt) {
        bf16x4 pk;
#pragma unroll
        for (int r = 0; r < 4; ++r) {
          const float p = __builtin_amdgcn_exp2f(st[m][kt][r] - mi[m]);
          sum += p;
          pk[r] = (__bf16)p;
        }
        const int row = m * 16 + l16;
        *reinterpret_cast<bf16x4*>(
            &Pl[wave][row * 64 + ((kt * 16 + g8 * 4) ^ cswz)]) = pk;
      }
      sum += __shfl_xor(sum, 16);
      sum += __shfl_xor(sum, 32);
      li[m] = li[m] * alpha[m] + sum;
    }

#pragma unroll
    for (int m = 0; m < 4; ++m) {
      if (dor[m]) {
        f32x4 al;
#pragma unroll
        for (int r = 0; r < 4; ++r) al[r] = __shfl(alpha[m], g8 * 4 + r);
#pragma unroll
        for (int nt = 0; nt < 4; ++nt) {
          f32x4 t = o[m][nt];
          t[0] *= al[0]; t[1] *= al[1]; t[2] *= al[2]; t[3] *= al[3];
          o[m][nt] = t;
        }
      }
    }

    // O += P V
#pragma unroll
    for (int nt = 0; nt < 4; ++nt) {
      const bf16x8 vf0 = *reinterpret_cast<const bf16x8*>(
          &Vl[buf][(nt * 16 + l16) * 64 + ((g8 * 8) ^ cswz)]);
      const bf16x8 vf1 = *reinterpret_cast<const bf16x8*>(
          &Vl[buf][(nt * 16 + l16) * 64 + ((32 + g8 * 8) ^ cswz)]);
#pragma unroll
      for (int m = 0; m < 4; ++m) {
        const bf16x8 pf0 = *reinterpret_cast<const bf16x8*>(
            &Pl[wave][(m * 16 + l16) * 64 + ((g8 * 8) ^ cswz)]);
        const bf16x8 pf1 = *reinterpret_cast<const bf16x8*>(
            &Pl[wave][(m * 16 + l16) * 64 + ((32 + g8 * 8) ^ cswz)]);
        o[m][nt] = __builtin_amdgcn_mfma_f32_16x16x32_bf16(pf0, vf0, o[m][nt], 0, 0, 0);
        o[m][nt] = __builtin_amdgcn_mfma_f32_16x16x32_bf16(pf1, vf1, o[m][nt], 0, 0, 0);
      }
    }

    wait_vm<0>();
    block_bar();
  }

#pragma unroll
  for (int m = 0; m < 4; ++m) {
    f32x4 ld;
#pragma unroll
    for (int r = 0; r < 4; ++r) ld[r] = 1.0f / __shfl(li[m], g8 * 4 + r);
#pragma unroll
    for (int nt = 0; nt < 4; ++nt)
#pragma unroll
      for (int r = 0; r < 4; ++r) {
        const __bf16 v = (__bf16)(o[m][nt][r] * ld[r]);
        ctx[(rowB + q0 + m * 16 + g8 * 4 + r) * D_MODEL + colH + nt * 16 + l16] =
            __builtin_bit_cast(u16, v);
      }
  }
}

extern "C" void kernel_launch(void* const* d_in, const int* in_sizes, int n_in,
                              void* d_out, int out_size, void* d_ws, size_t ws_size,
                              hipStream_t stream) {
  const float* x   = (const float*)d_in[0];
  const float* wq  = (const float*)d_in[1];
  const float* wk  = (const float*)d_in[2];
  const float* wv  = (const float*)d_in[3];
  const float* wo  = (const float*)d_in[4];
  const float* bo  = (const float*)d_in[5];
  const float* l1g = (const float*)d_in[6];
  const float* l1b = (const float*)d_in[7];
  const float* l2g = (const float*)d_in[8];
  const float* l2b = (const float*)d_in[9];
  const float* w1  = (const float*)d_in[10];
  const float* b1  = (const float*)d_in[11];
  const float* w2  = (const float*)d_in[12];
  const float* b2  = (const float*)d_in[13];
  float* outp = (float*)d_out;

  uint8_t* ws = (uint8_t*)d_ws;
  const size_t MB = 1024 * 1024;
  u16* wqkvt = (u16*)(ws + 0 * MB);   // fused [3072][1024]: wq|wk|wv transposed
  u16* wqt   = wqkvt;
  u16* wkt   = (u16*)(ws + 2 * MB);
  u16* wvt   = (u16*)(ws + 4 * MB);
  u16* wot   = (u16*)(ws + 6 * MB);
  u16* w1t   = (u16*)(ws + 8 * MB);   // [4096][1024]
  u16* w2t   = (u16*)(ws + 16 * MB);  // [1024][4096]
  u16* xn    = (u16*)(ws + 24 * MB);  // [8192][1024]; reused as ctx after QKV
  u16* qbuf  = (u16*)(ws + 40 * MB);  // [8192][1024]; reused as h after attention
  u16* kbuf  = (u16*)(ws + 56 * MB);
  u16* vbufT = (u16*)(ws + 72 * MB);  // [4][1024][2048] transposed V
  u16* ctx   = xn;
  u16* hbuf  = qbuf;
  u16* ffh   = kbuf;                  // [8192][4096] overlays kbuf.. (vbufT dead by then)

  dim3 blk(256);
  dim3 blk5(512);

  // weights -> bf16 transposed; wq carries 0.125*log2(e) (attention scale + exp2 conv)
  wconv_kernel<<<dim3(32, 32), blk, 0, stream>>>(wq, wqt, 1024, 1024, 0.18033688011112042f);
  wconv_kernel<<<dim3(32, 32), blk, 0, stream>>>(wk, wkt, 1024, 1024, 1.0f);
  wconv_kernel<<<dim3(32, 32), blk, 0, stream>>>(wv, wvt, 1024, 1024, 1.0f);
  wconv_kernel<<<dim3(32, 32), blk, 0, stream>>>(wo, wot, 1024, 1024, 1.0f);
  wconv_kernel<<<dim3(128, 32), blk, 0, stream>>>(w1, w1t, 1024, 4096, 1.0f);
  wconv_kernel<<<dim3(32, 128), blk, 0, stream>>>(w2, w2t, 4096, 1024, 1.0f);

  // xn = LN1(x)
  ln_kernel<<<MROWS, blk, 0, stream>>>(x, xn, l1g, l1b);

  // fused QKV projection: [8192,1024] x [3072,1024]^T; q,k row-major, v transposed
  gemm8p_kernel<128, 4><<<dim3(12, 64), blk5, 0, stream>>>(
      xn, wqkvt, 3072, 1024, nullptr, nullptr, nullptr, qbuf, kbuf, vbufT);

  // ctx = softmax(QK^T/8) V
  attn_kernel<<<dim3(8, 64), blk, 0, stream>>>(qbuf, kbuf, vbufT, ctx);

  // xt = x + ctx@wo + bo   (-> d_out, f32)
  gemm8p_kernel<128, 1><<<dim3(4, 64), blk5, 0, stream>>>(
      ctx, wot, 1024, 1024, bo, x, outp, nullptr, nullptr, nullptr);

  // h = LN2(xt)
  ln_kernel<<<MROWS, blk, 0, stream>>>(outp, hbuf, l2g, l2b);

  // ffh = relu(h@w1 + b1)
  gemm8p_kernel<256, 2><<<dim3(16, 32), blk5, 0, stream>>>(
      hbuf, w1t, 4096, 1024, b1, nullptr, nullptr, ffh, nullptr, nullptr);

  // out = xt + ffh@w2 + b2  (in-place on d_out)
  gemm8p_kernel<128, 1><<<dim3(4, 64), blk5, 0, stream>>>(
      ffh, w2t, 1024, 4096, b2, outp, outp, nullptr, nullptr, nullptr);
}

// Round 9
// 538.178 us; speedup vs baseline: 1.0651x; 1.0651x over previous
//
#include <hip/hip_runtime.h>
#include <stdint.h>

typedef __attribute__((ext_vector_type(8))) __bf16 bf16x8;
typedef __attribute__((ext_vector_type(4))) __bf16 bf16x4;
typedef __attribute__((ext_vector_type(4))) float f32x4;
typedef unsigned short u16;

#define D_MODEL 1024
#define D_FF 4096
#define SEQ 2048
#define NHEAD 16
#define DH 64
#define MROWS 8192

__device__ __forceinline__ u16 f2bf(float f) {
  union { float f; unsigned u; } v; v.f = f;
  unsigned r = v.u + 0x7fffu + ((v.u >> 16) & 1u);
  return (u16)(r >> 16);
}

// async global->LDS, 16B per lane; lds dest wave-uniform base (+lane*16 implicit)
__device__ __forceinline__ void gload16(const u16* g, u16* l) {
  __builtin_amdgcn_global_load_lds((const __attribute__((address_space(1))) void*)(g),
                                   (__attribute__((address_space(3))) void*)(l),
                                   16, 0, 0);
}

// raw barrier (no vmcnt/lgkmcnt drain) + compiler memory fence both sides
__device__ __forceinline__ void block_bar() {
  asm volatile("" ::: "memory");
  __builtin_amdgcn_s_barrier();
  asm volatile("" ::: "memory");
}

template <int N>
__device__ __forceinline__ void wait_vm() {
  if constexpr (N == 6)      asm volatile("s_waitcnt vmcnt(6)" ::: "memory");
  else if constexpr (N == 4) asm volatile("s_waitcnt vmcnt(4)" ::: "memory");
  else if constexpr (N == 2) asm volatile("s_waitcnt vmcnt(2)" ::: "memory");
  else                       asm volatile("s_waitcnt vmcnt(0)" ::: "memory");
}

// ---------------- weight f32 [K][N] -> bf16 transposed [N][K] (optional scale) ----
__global__ __launch_bounds__(256)
void wconv_kernel(const float* __restrict__ W, u16* __restrict__ Wt, int K, int N,
                  float scale) {
  __shared__ u16 t[32][33];
  const int tid = threadIdx.x, tx = tid & 31, ty = tid >> 5;
  const int n0 = blockIdx.x * 32, k0 = blockIdx.y * 32;
#pragma unroll
  for (int i = 0; i < 4; ++i) {
    int k = ty + i * 8;
    t[k][tx] = f2bf(W[(size_t)(k0 + k) * N + n0 + tx] * scale);
  }
  __syncthreads();
#pragma unroll
  for (int i = 0; i < 4; ++i) {
    int n = ty + i * 8;
    Wt[(size_t)(n0 + n) * K + k0 + tx] = t[tx][n];
  }
}

// ---------------- layernorm: f32 [row][1024] -> bf16 ----------------
__global__ __launch_bounds__(256)
void ln_kernel(const float* __restrict__ x, u16* __restrict__ out,
               const float* __restrict__ g, const float* __restrict__ beta) {
  const int row = blockIdx.x, tid = threadIdx.x;
  const float4 v = reinterpret_cast<const float4*>(x + (size_t)row * D_MODEL)[tid];
  float s = v.x + v.y + v.z + v.w;
#pragma unroll
  for (int off = 32; off; off >>= 1) s += __shfl_down(s, off);
  __shared__ float red[8];
  if ((tid & 63) == 0) red[tid >> 6] = s;
  __syncthreads();
  const float mu = (red[0] + red[1] + red[2] + red[3]) * (1.0f / D_MODEL);
  const float dx = v.x - mu, dy = v.y - mu, dz = v.z - mu, dw = v.w - mu;
  float sq = dx * dx + dy * dy + dz * dz + dw * dw;
#pragma unroll
  for (int off = 32; off; off >>= 1) sq += __shfl_down(sq, off);
  if ((tid & 63) == 0) red[4 + (tid >> 6)] = sq;
  __syncthreads();
  const float var = (red[4] + red[5] + red[6] + red[7]) * (1.0f / D_MODEL);
  const float rs = rsqrtf(var + 1e-5f);
  const float4 gv = reinterpret_cast<const float4*>(g)[tid];
  const float4 bv = reinterpret_cast<const float4*>(beta)[tid];
  ushort4 ov;
  ov.x = f2bf(dx * rs * gv.x + bv.x);
  ov.y = f2bf(dy * rs * gv.y + bv.y);
  ov.z = f2bf(dz * rs * gv.z + bv.z);
  ov.w = f2bf(dw * rs * gv.w + bv.w);
  reinterpret_cast<ushort4*>(out + (size_t)row * D_MODEL)[tid] = ov;
}

// ======== 8-phase TN GEMM (m201 template): 256x256 tile, BK=64, 8 waves (2x4) ====
// Used for W1 only (BM=256). EPI 2: relu(C + bias[col]) -> bf16 outb
template <int BM, int EPI>
__global__ __launch_bounds__(512, 2)
void gemm8p_kernel(const u16* __restrict__ A, const u16* __restrict__ Bt,
                   int N, int K,
                   const float* __restrict__ bias,
                   const float* __restrict__ res,
                   float* __restrict__ outf, u16* __restrict__ outb,
                   u16* __restrict__ outb2, u16* __restrict__ outb3) {
  constexpr int WM = BM / 2;
  constexpr int MREP = WM / 16;
  constexpr int MI = MREP / 4;
  constexpr int ACH = BM / 64;
  constexpr int VN = 6;
  __shared__ __align__(16) u16 Al[2][BM * 64];
  __shared__ __align__(16) u16 Bl[2][256 * 64];
  const int tid = threadIdx.x, lane = tid & 63, wave = tid >> 6;
  const int wr = wave >> 2, wc = wave & 3;
  const int l16 = lane & 15, g8 = lane >> 4;
  const int srw = lane >> 3;
  const int scl = ((lane & 7) ^ (lane >> 3)) * 8;
  const int swz = (l16 & 7) << 3;
  const int mBase = blockIdx.y * BM, nBase = blockIdx.x * 256;
  const int nt = K >> 6;

  f32x4 acc[MREP][4];
#pragma unroll
  for (int mi = 0; mi < MREP; ++mi)
#pragma unroll
    for (int nj = 0; nj < 4; ++nj) acc[mi][nj] = f32x4{0.f, 0.f, 0.f, 0.f};

  auto stageChunk = [&](int tile, int c) {
    if (tile >= nt) return;
    const int buf = tile & 1;
    if (c < ACH) {
      const int r0 = c * 64 + wave * 8;
      gload16(A + (size_t)(mBase + r0 + srw) * K + tile * 64 + scl,
              &Al[buf][r0 * 64]);
    } else {
      const int r0 = (c - ACH) * 64 + wave * 8;
      gload16(Bt + (size_t)(nBase + r0 + srw) * K + tile * 64 + scl,
              &Bl[buf][r0 * 64]);
    }
  };

  constexpr int STO256[16] = {1,1, 2,2, 2,2, 2,2, 2,2, 3,3, 3,3, 3,3};
  constexpr int STC256[16] = {1,3, 4,5, 6,7, 0,2, 1,3, 4,5, 6,7, 0,2};
  constexpr int P0_256[8] = {4,5,6,7,0,2,1,3};
  constexpr int P1_256[6] = {4,5,6,7,0,2};
#pragma unroll
  for (int i = 0; i < 8; ++i) stageChunk(0, P0_256[i]);
#pragma unroll
  for (int i = 0; i < 6; ++i) stageChunk(1, P1_256[i]);
  wait_vm<VN>();
  block_bar();

  for (int T = 0; T < nt; T += 2) {
    bf16x8 bfr[4][2];
#pragma unroll
    for (int p = 0; p < 8; ++p) {
      const int q = p & 3;
      const int buf = p >> 2;
      if (q == 0) {
#pragma unroll
        for (int nj = 0; nj < 4; ++nj)
#pragma unroll
          for (int ks = 0; ks < 2; ++ks) {
            const int rb = wc * 64 + nj * 16 + l16;
            bfr[nj][ks] = *reinterpret_cast<const bf16x8*>(
                &Bl[buf][rb * 64 + ((ks * 32 + g8 * 8) ^ swz)]);
          }
      }
      bf16x8 af[MI][2];
#pragma unroll
      for (int i = 0; i < MI; ++i)
#pragma unroll
        for (int ks = 0; ks < 2; ++ks) {
          const int ra = wr * WM + (q * MI + i) * 16 + l16;
          af[i][ks] = *reinterpret_cast<const bf16x8*>(
              &Al[buf][ra * 64 + ((ks * 32 + g8 * 8) ^ swz)]);
        }
      stageChunk(T + STO256[2 * p], STC256[2 * p]);
      stageChunk(T + STO256[2 * p + 1], STC256[2 * p + 1]);
      block_bar();
      __builtin_amdgcn_s_setprio(1);
#pragma unroll
      for (int i = 0; i < MI; ++i)
#pragma unroll
        for (int nj = 0; nj < 4; ++nj)
#pragma unroll
          for (int ks = 0; ks < 2; ++ks)
            acc[q * MI + i][nj] = __builtin_amdgcn_mfma_f32_16x16x32_bf16(
                af[i][ks], bfr[nj][ks], acc[q * MI + i][nj], 0, 0, 0);
      __builtin_amdgcn_s_setprio(0);
      if (p == 3) {
        if (T + 2 < nt) wait_vm<VN>(); else wait_vm<0>();
      } else if (p == 7) {
        wait_vm<VN>();
      }
      block_bar();
    }
  }

#pragma unroll
  for (int mi = 0; mi < MREP; ++mi)
#pragma unroll
    for (int nj = 0; nj < 4; ++nj) {
      const int colB = wc * 64 + nj * 16 + l16;
      const int row0 = mBase + wr * WM + mi * 16 + g8 * 4;
      const int col = nBase + colB;
      const float bv = bias[col];
#pragma unroll
      for (int r = 0; r < 4; ++r) {
        const size_t idx = (size_t)(row0 + r) * N + col;
        const float vv = acc[mi][nj][r];
        if (EPI == 1) {
          outf[idx] = vv + bv + res[idx];
        } else {
          const float tv = vv + bv;
          outb[idx] = f2bf(tv > 0.f ? tv : 0.f);
        }
      }
    }
}

// ======== 4-wave 128x128 TN GEMM: BK=64, dbuf, 2 blocks/CU (64 KiB LDS) ========
// 8 phases / 2 K-tiles; per phase: 1 A-slab ds_read (+8 B reads at q==0),
// 2 stage issues, 8 MFMA. Counted vmcnt chain: p1:4, p3:2, p5:4, p7:2 (tail 0).
// Mechanism: 2 independent blocks/CU cover each other's barrier bubbles (m114).
// EPI 1: C + bias[col] + res[idx] -> f32 outf (res may alias outf)
// EPI 4: fused QKV: col seg 0 -> outb, 1 -> outb2 (row-major), 2 -> outb3 transposed
template <int EPI>
__global__ __launch_bounds__(256, 2)
void gemm4w_kernel(const u16* __restrict__ A, const u16* __restrict__ Bt,
                   int N, int K,
                   const float* __restrict__ bias,
                   const float* __restrict__ res,
                   float* __restrict__ outf, u16* __restrict__ outb,
                   u16* __restrict__ outb2, u16* __restrict__ outb3) {
  __shared__ __align__(16) u16 Al[2][128 * 64];
  __shared__ __align__(16) u16 Bl[2][128 * 64];
  const int tid = threadIdx.x, lane = tid & 63, wave = tid >> 6;
  const int wr = wave >> 1, wc = wave & 1;
  const int l16 = lane & 15, g8 = lane >> 4;
  const int srw = lane >> 3;
  const int scl = ((lane & 7) ^ (lane >> 3)) * 8;
  const int swz = (l16 & 7) << 3;
  const int mBase = blockIdx.y * 128, nBase = blockIdx.x * 128;
  const int nt = K >> 6;

  f32x4 acc[4][4];
#pragma unroll
  for (int mi = 0; mi < 4; ++mi)
#pragma unroll
    for (int nj = 0; nj < 4; ++nj) acc[mi][nj] = f32x4{0.f, 0.f, 0.f, 0.f};

  // A chunk q covers rows {q*16..+15} (waves 0,1) U {64+q*16..+15} (waves 2,3):
  // exactly the rows phase q's MFMA reads (ra = wr*64 + q*16 + l16).
  auto stage2A = [&](int tile, int q0) {
    if (tile >= nt) return;
    const int b = tile & 1;
#pragma unroll
    for (int qq = 0; qq < 2; ++qq) {
      const int row0 = ((wave & 2) ? 64 : 0) + (q0 + qq) * 16 + (wave & 1) * 8;
      gload16(A + (size_t)(mBase + row0 + srw) * K + tile * 64 + scl,
              &Al[b][row0 * 64]);
    }
  };
  auto stage2B = [&](int tile, int b0) {
    if (tile >= nt) return;
    const int b = tile & 1;
#pragma unroll
    for (int bb = 0; bb < 2; ++bb) {
      const int row0 = (b0 + bb) * 32 + wave * 8;
      gload16(Bt + (size_t)(nBase + row0 + srw) * K + tile * 64 + scl,
              &Bl[b][row0 * 64]);
    }
  };

  // prologue: tile 0 (B first, then A slabs 0-3); confirm B + A01 before p0
  stage2B(0, 0); stage2B(0, 2); stage2A(0, 0); stage2A(0, 2);
  wait_vm<2>();
  block_bar();

  for (int T = 0; T < nt; T += 2) {
    bf16x8 bfr[4][2];
#pragma unroll
    for (int p = 0; p < 8; ++p) {
      const int q = p & 3;
      const int buf = p >> 2;
      const int tO = T + 1 + buf;      // staged tile; lands in buf^1
      if (q == 0) {
#pragma unroll
        for (int nj = 0; nj < 4; ++nj)
#pragma unroll
          for (int ks = 0; ks < 2; ++ks) {
            const int rb = wc * 64 + nj * 16 + l16;
            bfr[nj][ks] = *reinterpret_cast<const bf16x8*>(
                &Bl[buf][rb * 64 + ((ks * 32 + g8 * 8) ^ swz)]);
          }
      }
      bf16x8 af[2];
#pragma unroll
      for (int ks = 0; ks < 2; ++ks) {
        const int ra = wr * 64 + q * 16 + l16;
        af[ks] = *reinterpret_cast<const bf16x8*>(
            &Al[buf][ra * 64 + ((ks * 32 + g8 * 8) ^ swz)]);
      }
      if (q == 0)      stage2B(tO, 0);
      else if (q == 1) stage2B(tO, 2);
      else if (q == 2) stage2A(tO, 0);
      else             stage2A(tO, 2);
      block_bar();
      __builtin_amdgcn_s_setprio(1);
#pragma unroll
      for (int nj = 0; nj < 4; ++nj)
#pragma unroll
        for (int ks = 0; ks < 2; ++ks)
          acc[q][nj] = __builtin_amdgcn_mfma_f32_16x16x32_bf16(
              af[ks], bfr[nj][ks], acc[q][nj], 0, 0, 0);
      __builtin_amdgcn_s_setprio(0);
      if (p == 1) {
        wait_vm<4>();                                    // T's A23 landed (for p2/p3)
      } else if (p == 3) {
        wait_vm<2>();                                    // T+1 B + A01 landed (for p4/p5)
      } else if (p == 5) {
        if (T + 2 < nt) wait_vm<4>(); else wait_vm<0>(); // T+1 A23 landed (for p6/p7)
      } else if (p == 7) {
        if (T + 2 < nt) wait_vm<2>(); else wait_vm<0>(); // T+2 B + A01 landed (next p0)
      }
      block_bar();
    }
  }

#pragma unroll
  for (int mi = 0; mi < 4; ++mi)
#pragma unroll
    for (int nj = 0; nj < 4; ++nj) {
      const int colB = wc * 64 + nj * 16 + l16;
      const int row0 = mBase + wr * 64 + mi * 16 + g8 * 4;
      if (EPI == 4) {
        const int seg = nBase >> 10;                 // 0=q 1=k 2=v
        const int c = (nBase & 1023) + colB;
        if (seg == 2) {
          const int bi = row0 >> 11, s = row0 & 2047;
          ushort4 pk;
          pk.x = f2bf(acc[mi][nj][0]);
          pk.y = f2bf(acc[mi][nj][1]);
          pk.z = f2bf(acc[mi][nj][2]);
          pk.w = f2bf(acc[mi][nj][3]);
          *reinterpret_cast<ushort4*>(outb3 + ((size_t)(bi << 10) + c) * SEQ + s) = pk;
        } else {
          u16* o = (seg == 0) ? outb : outb2;
#pragma unroll
          for (int r = 0; r < 4; ++r)
            o[(size_t)(row0 + r) * D_MODEL + c] = f2bf(acc[mi][nj][r]);
        }
      } else {
        const int col = nBase + colB;
        const float bv = bias[col];
#pragma unroll
        for (int r = 0; r < 4; ++r) {
          const size_t idx = (size_t)(row0 + r) * N + col;
          outf[idx] = acc[mi][nj][r] + bv + res[idx];
        }
      }
    }
}

// ---------------- flash attention: 4 waves x 32 q-rows (round-7 config) ----------
// Swapped QK^T; async dbuf KV; exp2 (scale folded in wq); defer-max (T13).
__global__ __launch_bounds__(256)
void attn_kernel(const u16* __restrict__ qb, const u16* __restrict__ kb,
                 const u16* __restrict__ vb, u16* __restrict__ ctx) {
  __shared__ __align__(16) u16 Kl[2][64 * 64];
  __shared__ __align__(16) u16 Vl[2][64 * 64];   // V^T tile: Vl[d][t]
  __shared__ __align__(16) u16 Pl[4][32 * 64];   // per-wave P: [q 32][kv 64]
  const int tid = threadIdx.x;
  const int lane = tid & 63, wave = tid >> 6, g8 = lane >> 4, l16 = lane & 15;
  const int b = blockIdx.y >> 4, h = blockIdx.y & 15;
  const int q0 = blockIdx.x * 128 + wave * 32;
  const size_t rowB = (size_t)b * SEQ;
  const int colH = h * DH;
  const size_t vtBase = (size_t)(b * 1024 + colH) * SEQ;
  const int srw = lane >> 3;
  const int scl = ((lane & 7) ^ (lane >> 3)) * 8;
  const int cswz = (l16 & 7) * 8;

  bf16x8 qf[2][2];
#pragma unroll
  for (int m = 0; m < 2; ++m)
#pragma unroll
    for (int ks = 0; ks < 2; ++ks)
      qf[m][ks] = *reinterpret_cast<const bf16x8*>(
          qb + (rowB + q0 + m * 16 + l16) * D_MODEL + colH + ks * 32 + g8 * 8);

  float mi[2] = {-1e30f, -1e30f}, li[2] = {0.f, 0.f};
  f32x4 o[2][4];
#pragma unroll
  for (int m = 0; m < 2; ++m)
#pragma unroll
    for (int nt = 0; nt < 4; ++nt) o[m][nt] = f32x4{0.f, 0.f, 0.f, 0.f};

  auto stageKV = [&](int t0, int buf) {
    if (t0 >= SEQ) return;
#pragma unroll
    for (int i = 0; i < 2; ++i) {
      const int r0 = wave * 16 + i * 8;
      gload16(kb + (rowB + t0 + r0 + srw) * D_MODEL + colH + scl, &Kl[buf][r0 * 64]);
      gload16(vb + vtBase + (size_t)(r0 + srw) * SEQ + t0 + scl, &Vl[buf][r0 * 64]);
    }
  };

  stageKV(0, 0);
  wait_vm<0>();
  block_bar();

  int buf = 0;
  for (int t0 = 0; t0 < SEQ; t0 += 64, buf ^= 1) {
    stageKV(t0 + 64, buf ^ 1);

    f32x4 st[2][4];
#pragma unroll
    for (int m = 0; m < 2; ++m)
#pragma unroll
      for (int kt = 0; kt < 4; ++kt) st[m][kt] = f32x4{0.f, 0.f, 0.f, 0.f};
#pragma unroll
    for (int kt = 0; kt < 4; ++kt) {
      const bf16x8 kf0 = *reinterpret_cast<const bf16x8*>(
          &Kl[buf][(kt * 16 + l16) * 64 + ((g8 * 8) ^ cswz)]);
      const bf16x8 kf1 = *reinterpret_cast<const bf16x8*>(
          &Kl[buf][(kt * 16 + l16) * 64 + ((32 + g8 * 8) ^ cswz)]);
#pragma unroll
      for (int m = 0; m < 2; ++m) {
        st[m][kt] = __builtin_amdgcn_mfma_f32_16x16x32_bf16(kf0, qf[m][0], st[m][kt], 0, 0, 0);
        st[m][kt] = __builtin_amdgcn_mfma_f32_16x16x32_bf16(kf1, qf[m][1], st[m][kt], 0, 0, 0);
      }
    }

    float alpha[2];
    bool dor[2];
#pragma unroll
    for (int m = 0; m < 2; ++m) {
      float pmax = st[m][0][0];
#pragma unroll
      for (int kt = 0; kt < 4; ++kt)
#pragma unroll
        for (int r = 0; r < 4; ++r) pmax = fmaxf(pmax, st[m][kt][r]);
      pmax = fmaxf(pmax, __shfl_xor(pmax, 16));
      pmax = fmaxf(pmax, __shfl_xor(pmax, 32));
      dor[m] = !__all(pmax - mi[m] <= 8.0f);
      alpha[m] = 1.0f;
      if (dor[m]) {
        const float mnew = fmaxf(mi[m], pmax);
        alpha[m] = __builtin_amdgcn_exp2f(mi[m] - mnew);
        mi[m] = mnew;
      }
      float sum = 0.f;
#pragma unroll
      for (int kt = 0; kt < 4; ++kt) {
        bf16x4 pk;
#pragma unroll
        for (int r = 0; r < 4; ++r) {
          const float p = __builtin_amdgcn_exp2f(st[m][kt][r] - mi[m]);
          sum += p;
          pk[r] = (__bf16)p;
        }
        const int row = m * 16 + l16;
        *reinterpret_cast<bf16x4*>(
            &Pl[wave][row * 64 + ((kt * 16 + g8 * 4) ^ cswz)]) = pk;
      }
      sum += __shfl_xor(sum, 16);
      sum += __shfl_xor(sum, 32);
      li[m] = li[m] * alpha[m] + sum;
    }

#pragma unroll
    for (int m = 0; m < 2; ++m) {
      if (dor[m]) {
        f32x4 al;
#pragma unroll
        for (int r = 0; r < 4; ++r) al[r] = __shfl(alpha[m], g8 * 4 + r);
#pragma unroll
        for (int nt = 0; nt < 4; ++nt) {
          f32x4 t = o[m][nt];
          t[0] *= al[0]; t[1] *= al[1]; t[2] *= al[2]; t[3] *= al[3];
          o[m][nt] = t;
        }
      }
    }

    bf16x8 pf[2][2];
#pragma unroll
    for (int m = 0; m < 2; ++m)
#pragma unroll
      for (int ks = 0; ks < 2; ++ks)
        pf[m][ks] = *reinterpret_cast<const bf16x8*>(
            &Pl[wave][(m * 16 + l16) * 64 + ((ks * 32 + g8 * 8) ^ cswz)]);
#pragma unroll
    for (int nt = 0; nt < 4; ++nt) {
      const bf16x8 vf0 = *reinterpret_cast<const bf16x8*>(
          &Vl[buf][(nt * 16 + l16) * 64 + ((g8 * 8) ^ cswz)]);
      const bf16x8 vf1 = *reinterpret_cast<const bf16x8*>(
          &Vl[buf][(nt * 16 + l16) * 64 + ((32 + g8 * 8) ^ cswz)]);
#pragma unroll
      for (int m = 0; m < 2; ++m) {
        o[m][nt] = __builtin_amdgcn_mfma_f32_16x16x32_bf16(pf[m][0], vf0, o[m][nt], 0, 0, 0);
        o[m][nt] = __builtin_amdgcn_mfma_f32_16x16x32_bf16(pf[m][1], vf1, o[m][nt], 0, 0, 0);
      }
    }

    wait_vm<0>();
    block_bar();
  }

#pragma unroll
  for (int m = 0; m < 2; ++m) {
    f32x4 ld;
#pragma unroll
    for (int r = 0; r < 4; ++r) ld[r] = 1.0f / __shfl(li[m], g8 * 4 + r);
#pragma unroll
    for (int nt = 0; nt < 4; ++nt)
#pragma unroll
      for (int r = 0; r < 4; ++r) {
        const __bf16 v = (__bf16)(o[m][nt][r] * ld[r]);
        ctx[(rowB + q0 + m * 16 + g8 * 4 + r) * D_MODEL + colH + nt * 16 + l16] =
            __builtin_bit_cast(u16, v);
      }
  }
}

extern "C" void kernel_launch(void* const* d_in, const int* in_sizes, int n_in,
                              void* d_out, int out_size, void* d_ws, size_t ws_size,
                              hipStream_t stream) {
  const float* x   = (const float*)d_in[0];
  const float* wq  = (const float*)d_in[1];
  const float* wk  = (const float*)d_in[2];
  const float* wv  = (const float*)d_in[3];
  const float* wo  = (const float*)d_in[4];
  const float* bo  = (const float*)d_in[5];
  const float* l1g = (const float*)d_in[6];
  const float* l1b = (const float*)d_in[7];
  const float* l2g = (const float*)d_in[8];
  const float* l2b = (const float*)d_in[9];
  const float* w1  = (const float*)d_in[10];
  const float* b1  = (const float*)d_in[11];
  const float* w2  = (const float*)d_in[12];
  const float* b2  = (const float*)d_in[13];
  float* outp = (float*)d_out;

  uint8_t* ws = (uint8_t*)d_ws;
  const size_t MB = 1024 * 1024;
  u16* wqkvt = (u16*)(ws + 0 * MB);   // fused [3072][1024]: wq|wk|wv transposed
  u16* wqt   = wqkvt;
  u16* wkt   = (u16*)(ws + 2 * MB);
  u16* wvt   = (u16*)(ws + 4 * MB);
  u16* wot   = (u16*)(ws + 6 * MB);
  u16* w1t   = (u16*)(ws + 8 * MB);   // [4096][1024]
  u16* w2t   = (u16*)(ws + 16 * MB);  // [1024][4096]
  u16* xn    = (u16*)(ws + 24 * MB);  // [8192][1024]; reused as ctx after QKV
  u16* qbuf  = (u16*)(ws + 40 * MB);  // [8192][1024]; reused as h after attention
  u16* kbuf  = (u16*)(ws + 56 * MB);
  u16* vbufT = (u16*)(ws + 72 * MB);  // [4][1024][2048] transposed V
  u16* ctx   = xn;
  u16* hbuf  = qbuf;
  u16* ffh   = kbuf;                  // [8192][4096] overlays kbuf.. (vbufT dead by then)

  dim3 blk(256);
  dim3 blk5(512);

  // weights -> bf16 transposed; wq carries 0.125*log2(e) (attention scale + exp2 conv)
  wconv_kernel<<<dim3(32, 32), blk, 0, stream>>>(wq, wqt, 1024, 1024, 0.18033688011112042f);
  wconv_kernel<<<dim3(32, 32), blk, 0, stream>>>(wk, wkt, 1024, 1024, 1.0f);
  wconv_kernel<<<dim3(32, 32), blk, 0, stream>>>(wv, wvt, 1024, 1024, 1.0f);
  wconv_kernel<<<dim3(32, 32), blk, 0, stream>>>(wo, wot, 1024, 1024, 1.0f);
  wconv_kernel<<<dim3(128, 32), blk, 0, stream>>>(w1, w1t, 1024, 4096, 1.0f);
  wconv_kernel<<<dim3(32, 128), blk, 0, stream>>>(w2, w2t, 4096, 1024, 1.0f);

  // xn = LN1(x)
  ln_kernel<<<MROWS, blk, 0, stream>>>(x, xn, l1g, l1b);

  // fused QKV projection: [8192,1024] x [3072,1024]^T; q,k row-major, v transposed
  gemm4w_kernel<4><<<dim3(24, 64), blk, 0, stream>>>(
      xn, wqkvt, 3072, 1024, nullptr, nullptr, nullptr, qbuf, kbuf, vbufT);

  // ctx = softmax(QK^T/8) V
  attn_kernel<<<dim3(16, 64), blk, 0, stream>>>(qbuf, kbuf, vbufT, ctx);

  // xt = x + ctx@wo + bo   (-> d_out, f32)
  gemm4w_kernel<1><<<dim3(8, 64), blk, 0, stream>>>(
      ctx, wot, 1024, 1024, bo, x, outp, nullptr, nullptr, nullptr);

  // h = LN2(xt)
  ln_kernel<<<MROWS, blk, 0, stream>>>(outp, hbuf, l2g, l2b);

  // ffh = relu(h@w1 + b1)
  gemm8p_kernel<256, 2><<<dim3(16, 32), blk5, 0, stream>>>(
      hbuf, w1t, 4096, 1024, b1, nullptr, nullptr, ffh, nullptr, nullptr);

  // out = xt + ffh@w2 + b2  (in-place on d_out)
  gemm4w_kernel<1><<<dim3(8, 64), blk, 0, stream>>>(
      ffh, w2t, 1024, 4096, b2, outp, outp, nullptr, nullptr, nullptr);
}